// Round 25
// baseline (93.183 us; speedup 1.0000x reference)
//
#include <hip/hip_runtime.h>

// ---------------------------------------------------------------------------
// Fused attention block: qkv GEMM+RoPE+layout -> causal SDPA (MFMA) -> out GEMM
// B=2 S=2048 D=1024 H=16 DH=64. bf16 MFMA everywhere.
// MFMA fragment mapping (verified r1-r13): A/B-frag outer=lane&15, k=oct*8+e;
// C/D row=oct*4+r, col=lane&15.
// r25: gemm_fused -> 512 threads (8 waves, 4Mx2N, per-wave 32x64): halves the
//      per-wave serial chain and doubles occupancy to 24 waves/CU (stalls
//      were correlated at 4-wave granularity). Same 128x128 tile, 3-slot
//      ring; staging = 2 gload16 issues/tile, vmcnt(2)/0 ladder. Epilogue
//      remapped (RoPE i<2; V: 8 groups, 2 per 64x64 tile, disjoint qq).
//      attn/gemm2/prologue byte-identical to r24 (93.0us best).
// ---------------------------------------------------------------------------

typedef __bf16 bf16x8 __attribute__((ext_vector_type(8)));
typedef float f32x4 __attribute__((ext_vector_type(4)));

__device__ __forceinline__ unsigned short f2b(float f) {
  unsigned int u = __builtin_bit_cast(unsigned int, f);
  unsigned int lsb = (u >> 16) & 1u;
  u += 0x7fffu + lsb;  // round-to-nearest-even
  return (unsigned short)(u >> 16);
}
__device__ __forceinline__ float b2f(unsigned short h) {
  unsigned int u = ((unsigned int)h) << 16;
  return __builtin_bit_cast(float, u);
}
__device__ __forceinline__ unsigned int pk2(float a, float b) {
  return (unsigned int)f2b(a) | ((unsigned int)f2b(b) << 16);
}
__device__ __forceinline__ unsigned int cvtpk(float lo, float hi) {
  unsigned int r;
  asm("v_cvt_pk_bf16_f32 %0, %1, %2" : "=v"(r) : "v"(lo), "v"(hi));
  return r;
}
__device__ __forceinline__ void gload16(const void* g, void* l) {
  __builtin_amdgcn_global_load_lds(
      (const __attribute__((address_space(1))) unsigned int*)g,
      (__attribute__((address_space(3))) unsigned int*)l, 16, 0, 0);
}

// ---- fused prologue: convert | trig table | transpose wq | transpose wo ----
__global__ __launch_bounds__(256) void prologue_kernel(
    const float* __restrict__ x, unsigned short* __restrict__ xb,
    const float* __restrict__ freqs, float* __restrict__ cosT,
    float* __restrict__ sinT, const float* __restrict__ w_qkv,
    unsigned short* __restrict__ wqT, const float* __restrict__ w_out,
    unsigned short* __restrict__ woT) {
  __shared__ float tile[32][33];
  const int blk = blockIdx.x, tid = threadIdx.x;

  if (blk < 4096) {  // convert x (f32) -> xb (bf16), 4 elems/thread
    int i = (blk * 256 + tid) * 4;
    float4 v = *(const float4*)&x[i];
    ushort4 o;
    o.x = f2b(v.x); o.y = f2b(v.y); o.z = f2b(v.z); o.w = f2b(v.w);
    *(ushort4*)&xb[i] = o;
    return;
  }
  if (blk < 4608) {  // cos/sin tables (131072 elems)
    int i = (blk - 4096) * 256 + tid;
    float f = freqs[i];
    cosT[i] = cosf(f);
    sinT[i] = sinf(f);
    return;
  }
  // transpose [K][N] f32 -> [N][K] bf16
  const float* src;
  unsigned short* dst;
  int K, N, bx, by;
  if (blk < 7680) {
    src = w_qkv; dst = wqT; K = 1024; N = 3072;
    const int t = blk - 4608;
    bx = t % 96; by = t / 96;
  } else {
    src = w_out; dst = woT; K = 1024; N = 1024;
    const int t = blk - 7680;
    bx = t % 32; by = t / 32;
  }
  const int n0 = bx * 32, k0 = by * 32;
  const int c = tid & 31, r4 = tid >> 5;
#pragma unroll
  for (int p = 0; p < 4; ++p) {
    int r = r4 + p * 8;
    tile[r][c] = src[(size_t)(k0 + r) * N + n0 + c];
  }
  __syncthreads();
#pragma unroll
  for (int p = 0; p < 4; ++p) {
    int r = r4 + p * 8;
    dst[(size_t)(n0 + r) * K + k0 + c] = f2b(tile[c][r]);
  }
}

// ------ fused qkv GEMM + RoPE + layout: 128x128 tile, 512 thr, 3-slot ring --
// 8 waves (4M x 2N), per-wave 32x64 (acc 2x4). Ring of 3 LDS slots of
// {A[128][32], B[128][32]} = 16 KB -> 48 KB -> 3 blocks/CU = 24 waves/CU.
// Staging: 2 gload16 issues/tile (512 thr x 16 B = one matrix half each);
// counted vmcnt(2), tail vmcnt(0). Epilogue: part block-uniform; wave's 64
// cols = one head; V via 4 x 64x66 vtiles, 8 write-groups (2/tile).
__global__ __launch_bounds__(512, 6) void gemm_fused(
    const unsigned short* __restrict__ A, const unsigned short* __restrict__ BT,
    unsigned short* __restrict__ Qb, unsigned short* __restrict__ Kbp,
    unsigned short* __restrict__ Vtg, const float* __restrict__ cosT,
    const float* __restrict__ sinT) {
  extern __shared__ unsigned short L[];  // 3 slots x 8192 ushort = 48 KB
  const int K = 1024;
  const int tid = threadIdx.x, lane = tid & 63, w = tid >> 6;
  const int wr = w >> 1, wc = w & 1;     // 4 row-strips x 2 heads
  const int fr = lane & 15, oct = lane >> 4;

  const int m0 = blockIdx.y * 128, n0 = blockIdx.x * 128;

  // staging: thread covers row tid>>2 (0..127), chunk tid&3, swizzled source
  const int scol = ((tid & 3) ^ ((tid >> 3) & 3)) * 8;
  const size_t aR = (size_t)(m0 + (tid >> 2)) * K + scol;
  const size_t bR = (size_t)(n0 + (tid >> 2)) * K + scol;

  f32x4 acc[2][4] = {};
  const int T = K >> 5;  // 32

  for (int pt = 0; pt < 2; ++pt) {  // prologue: stage tiles 0,1
    unsigned short* Ln = &L[pt * 8192];
    const size_t gk = (size_t)pt * 32;
    gload16(&A[aR + gk], &Ln[tid * 8]);
    gload16(&BT[bR + gk], &Ln[4096 + tid * 8]);
  }

  int cs = 0;  // slot of tile t
  for (int t = 0; t < T; ++t) {
    if (t + 2 <= T) {
      asm volatile("s_waitcnt vmcnt(2)" ::: "memory");
    } else {
      asm volatile("s_waitcnt vmcnt(0)" ::: "memory");
    }
    __builtin_amdgcn_sched_barrier(0);
    __builtin_amdgcn_s_barrier();
    __builtin_amdgcn_sched_barrier(0);

    const unsigned short* Lb = &L[cs * 8192];
    const int sslot = (cs == 0) ? 2 : cs - 1;  // slot of tile t+2
    unsigned short* Ln = &L[sslot * 8192];
    const size_t gk = (size_t)(t + 2) * 32;
    const bool doStage = (t + 2 < T);

    bf16x8 af[2], bq[4];
#pragma unroll
    for (int i = 0; i < 2; ++i) {
      const int ra = wr * 32 + i * 16 + fr;
      af[i] = __builtin_bit_cast(
          bf16x8, *(const uint4*)&Lb[ra * 32 + ((oct ^ ((ra >> 1) & 3)) * 8)]);
    }
#pragma unroll
    for (int j = 0; j < 4; ++j) {
      const int rb = wc * 64 + j * 16 + fr;
      bq[j] = __builtin_bit_cast(
          bf16x8,
          *(const uint4*)&Lb[4096 + rb * 32 + ((oct ^ ((rb >> 1) & 3)) * 8)]);
    }
    if (doStage) {
      gload16(&A[aR + gk], &Ln[tid * 8]);
      gload16(&BT[bR + gk], &Ln[4096 + tid * 8]);
    }
    __builtin_amdgcn_s_setprio(1);
#pragma unroll
    for (int i = 0; i < 2; ++i)
#pragma unroll
      for (int j = 0; j < 4; ++j)
        acc[i][j] = __builtin_amdgcn_mfma_f32_16x16x32_bf16(af[i], bq[j], acc[i][j], 0, 0, 0);
    __builtin_amdgcn_s_setprio(0);

    cs = (cs == 2) ? 0 : cs + 1;
  }

  // ---- fused epilogue: RoPE q/k or transposed V, direct to Qb/Kb/Vtg ----
  const float QSCALE = 0.125f * 1.44269504f;
  const int part = n0 >> 10;               // block-uniform: 0=q, 1=k, 2=v
  const int hh = ((n0 & 1023) >> 6) + wc;  // wave's head
  if (part < 2) {
    unsigned short* dst = (part == 0) ? Qb : Kbp;
    const float scale = (part == 0) ? QSCALE : 1.0f;
#pragma unroll
    for (int i = 0; i < 2; ++i)
#pragma unroll
      for (int r = 0; r < 4; ++r) {
        const int m = m0 + wr * 32 + i * 16 + oct * 4 + r;
        const int bb = m >> 11, s = m & 2047;
        const size_t ob = ((size_t)(bb * 16 + hh) * 2048 + s) * 64;
#pragma unroll
        for (int j = 0; j < 2; ++j) {
          const int d = j * 16 + fr;
          const float lo = acc[i][j][r], hi = acc[i][j + 2][r];
          const float cl = cosT[s * 64 + d], sl = sinT[s * 64 + d];
          const float ch = cosT[s * 64 + 32 + d], sh = sinT[s * 64 + 32 + d];
          dst[ob + d] = f2b((lo * cl - hi * sl) * scale);
          dst[ob + 32 + d] = f2b((hi * ch + lo * sh) * scale);
        }
      }
  } else {
    __syncthreads();  // all waves done reading ring slots
    // stage into 4 tiles of 64x66 (= 33792 B <= 48 KB); vtile = row-half*2+head
    unsigned short* vt = L + ((wr >> 1) * 2 + wc) * 4224;
#pragma unroll
    for (int i = 0; i < 2; ++i)
#pragma unroll
      for (int r = 0; r < 4; ++r) {
        const int s64 = (wr & 1) * 32 + i * 16 + oct * 4 + r;
#pragma unroll
        for (int j = 0; j < 4; ++j) vt[s64 * 66 + j * 16 + fr] = f2b(acc[i][j][r]);
      }
    __syncthreads();
    // transposed + k-permuted write; 8 groups of 64 thr, 2 groups per tile
    const int tix2 = tid >> 6, d = tid & 63;
    const int tile = tix2 >> 1, qh = tix2 & 1;
    const unsigned short* tt = L + tile * 4224;
    const int mtile = m0 + (tile >> 1) * 64;
    const int bb = mtile >> 11, sb = (mtile & 2047) >> 6;
    const int hv = ((n0 & 1023) >> 6) + (tile & 1);
    const size_t vb = (((size_t)(bb * 16 + hv) * 32 + sb) * 64 + d) * 64;
#pragma unroll
    for (int q2 = 0; q2 < 2; ++q2) {
      const int qq = qh * 2 + q2;
#pragma unroll
      for (int g = 0; g < 4; ++g) {
        ushort4 u;
        u.x = tt[(qq * 16 + g * 4 + 0) * 66 + d];
        u.y = tt[(qq * 16 + g * 4 + 1) * 66 + d];
        u.z = tt[(qq * 16 + g * 4 + 2) * 66 + d];
        u.w = tt[(qq * 16 + g * 4 + 3) * 66 + d];
        *(ushort4*)&Vtg[vb + (qq >> 1) * 32 + g * 8 + (qq & 1) * 4] = u;
      }
    }
  }
}

// ---------------- ring-buffered bf16 GEMM for out GEMM (f32 C) -------------
__global__ __launch_bounds__(256, 2) void gemm2_ring(const unsigned short* __restrict__ A,
                                                     const unsigned short* __restrict__ BT,
                                                     float* __restrict__ C,
                                                     int M, int N, int K) {
  extern __shared__ unsigned short L[];  // 4 slots x 6144 ushort = 48 KB
  const int tid = threadIdx.x, lane = tid & 63, w = tid >> 6;
  const int wr = w >> 1, wc = w & 1;
  const int fr = lane & 15, oct = lane >> 4;
  const int m0 = blockIdx.y * 128, n0 = blockIdx.x * 64;

  const int sr = tid >> 2;
  const int scol = ((tid & 3) ^ ((tid >> 3) & 3)) * 8;  // swizzled src col
  const size_t aR0 = (size_t)(m0 + sr) * K + scol;
  const size_t aR1 = (size_t)(m0 + 64 + sr) * K + scol;
  const size_t bR0 = (size_t)(n0 + sr) * K + scol;

  f32x4 acc[4][2] = {};
  const int T = K >> 5;

  for (int pt = 0; pt < 3; ++pt) {  // prologue: stage tiles 0,1,2
    unsigned short* Ln = &L[pt * 6144];
    const size_t gk = (size_t)pt * 32;
    gload16(&A[aR0 + gk], &Ln[tid * 8]);
    gload16(&A[aR1 + gk], &Ln[2048 + tid * 8]);
    gload16(&BT[bR0 + gk], &Ln[4096 + tid * 8]);
  }

  for (int t = 0; t < T; ++t) {
    if (t + 3 <= T) {
      asm volatile("s_waitcnt vmcnt(6)" ::: "memory");
    } else if (t + 2 == T) {
      asm volatile("s_waitcnt vmcnt(3)" ::: "memory");
    } else {
      asm volatile("s_waitcnt vmcnt(0)" ::: "memory");
    }
    __builtin_amdgcn_sched_barrier(0);
    __builtin_amdgcn_s_barrier();
    __builtin_amdgcn_sched_barrier(0);

    const unsigned short* Lb = &L[(t & 3) * 6144];
    unsigned short* Ln = &L[((t + 3) & 3) * 6144];
    const size_t gk = (size_t)(t + 3) * 32;
    const bool doStage = (t + 3 < T);

    bf16x8 af[4], bq[2];
#pragma unroll
    for (int i = 0; i < 4; ++i) {
      const int ra = wr * 64 + i * 16 + fr;
      af[i] = __builtin_bit_cast(
          bf16x8, *(const uint4*)&Lb[ra * 32 + ((oct ^ ((ra >> 1) & 3)) * 8)]);
    }
#pragma unroll
    for (int j = 0; j < 2; ++j) {
      const int rb = wc * 32 + j * 16 + fr;
      bq[j] = __builtin_bit_cast(
          bf16x8,
          *(const uint4*)&Lb[4096 + rb * 32 + ((oct ^ ((rb >> 1) & 3)) * 8)]);
    }
    if (doStage) {
      gload16(&A[aR0 + gk], &Ln[tid * 8]);
      gload16(&A[aR1 + gk], &Ln[2048 + tid * 8]);
      gload16(&BT[bR0 + gk], &Ln[4096 + tid * 8]);
    }
    __builtin_amdgcn_s_setprio(1);
#pragma unroll
    for (int i = 0; i < 4; ++i)
#pragma unroll
      for (int j = 0; j < 2; ++j)
        acc[i][j] = __builtin_amdgcn_mfma_f32_16x16x32_bf16(af[i], bq[j], acc[i][j], 0, 0, 0);
    __builtin_amdgcn_s_setprio(0);
  }

#pragma unroll
  for (int i = 0; i < 4; ++i)
#pragma unroll
    for (int j = 0; j < 2; ++j)
#pragma unroll
      for (int r = 0; r < 4; ++r)
        C[(size_t)(m0 + wr * 64 + i * 16 + oct * 4 + r) * N + n0 + wc * 32 +
          j * 16 + fr] = acc[i][j][r];
}

// --------------------------- MFMA flash attention ---------------------------
// (r13 algorithm + XCD swizzle + XOR-swizzled stride-64 K/V LDS tiles)
__global__ __launch_bounds__(512, 4) void attn_mfma(const unsigned short* __restrict__ Qb,
                                                    const unsigned short* __restrict__ Kb,
                                                    const unsigned short* __restrict__ Vtg,
                                                    unsigned short* __restrict__ attnb) {
  extern __shared__ unsigned short KV[];  // [8][64][64], XOR-chunk-swizzled
  // XCD-bijective swizzle: all 16 qt0-blocks of one (h,b) K/V group -> 1 XCD
  const int bid = blockIdx.x + 16 * (blockIdx.y + 16 * blockIdx.z);
  const int xcd = bid & 7, slot = bid >> 3;
  const int qt0 = slot & 15;           // 0..15
  const int gq = xcd + 8 * (slot >> 4);  // 0..31 (h,b group)
  const int h = gq & 15, b = gq >> 4;
  const int qt1 = 31 - qt0;            // 16..31
  const int tid = threadIdx.x, lane = tid & 63, w = tid >> 6;
  const int fr = lane & 15, oct = lane >> 4;
  const int grp = w >> 2, wq = w & 3;
  const int nhA = 16 - qt0, nhB = 15 - qt0;

  const size_t bh = (size_t)(b * 16 + h);
  const unsigned short* Kbase = Kb + bh * 131072;
  const unsigned short* Vbase = Vtg + bh * 131072;

  const int qtP1 = grp ? qt1 : qt0;
  const unsigned short* Qp1 = Qb + (bh * 2048 + qtP1 * 64 + wq * 16 + fr) * 64;
  const bf16x8 qa0 = __builtin_bit_cast(bf16x8, *(const uint4*)(Qp1 + oct * 8));
  const bf16x8 qa1 = __builtin_bit_cast(bf16x8, *(const uint4*)(Qp1 + 32 + oct * 8));
  const unsigned short* Qp2 = Qb + (bh * 2048 + qt1 * 64 + wq * 16 + fr) * 64;
  const bf16x8 qb0 = __builtin_bit_cast(bf16x8, *(const uint4*)(Qp2 + oct * 8));
  const bf16x8 qb1 = __builtin_bit_cast(bf16x8, *(const uint4*)(Qp2 + 32 + oct * 8));

  // loop-invariant swizzled read-chunk offsets: row&7 == fr&7
  const int frx = fr & 7;
  const int rc0 = (oct ^ frx) * 8;        // logical chunk oct   (d 0..31)
  const int rc1 = ((4 + oct) ^ frx) * 8;  // logical chunk 4+oct (d 32..63)

  float m_prev = -1e30f;
  f32x4 acc[4] = {};
  f32x4 accl = {};

  uint4 onesu;
  onesu.x = 0x3F803F80u; onesu.y = 0x3F803F80u;
  onesu.z = 0x3F803F80u; onesu.w = 0x3F803F80u;
  const bf16x8 onesf = __builtin_bit_cast(bf16x8, onesu);

  auto tile_step = [&](int buf, bf16x8 q0, bf16x8 q1, bool domask) {
    const unsigned short* Kbuf = &KV[buf * 4096];
    const unsigned short* Vbuf = &KV[(4 + buf) * 4096];
    f32x4 s4[4];
    __builtin_amdgcn_s_setprio(1);
#pragma unroll
    for (int t = 0; t < 4; ++t) {
      bf16x8 kf0 = __builtin_bit_cast(bf16x8, *(const uint4*)&Kbuf[(t * 16 + fr) * 64 + rc0]);
      bf16x8 kf1 = __builtin_bit_cast(bf16x8, *(const uint4*)&Kbuf[(t * 16 + fr) * 64 + rc1]);
      f32x4 s = {};
      s = __builtin_amdgcn_mfma_f32_16x16x32_bf16(kf0, q0, s, 0, 0, 0);
      s = __builtin_amdgcn_mfma_f32_16x16x32_bf16(kf1, q1, s, 0, 0, 0);
      s4[t] = s;
    }
    __builtin_amdgcn_s_setprio(0);
    if (domask) {
#pragma unroll
      for (int t = 0; t < 4; ++t)
#pragma unroll
        for (int r = 0; r < 4; ++r)
          if (t * 16 + oct * 4 + r > wq * 16 + fr) s4[t][r] = -1e30f;
    }

    float pm = -1e30f;
#pragma unroll
    for (int t = 0; t < 4; ++t)
#pragma unroll
      for (int r = 0; r < 4; ++r) pm = fmaxf(pm, s4[t][r]);
    const bool need = __any(pm - m_prev > 11.0f);
    if (need) {
      float pmf = fmaxf(pm, __shfl_xor(pm, 16));
      pmf = fmaxf(pmf, __shfl_xor(pmf, 32));
      float mnew = fmaxf(m_prev, pmf);
      float cf = __builtin_amdgcn_exp2f(m_prev - mnew);
      m_prev = mnew;
      float cfr[4];
#pragma unroll
      for (int r = 0; r < 4; ++r) cfr[r] = __shfl(cf, oct * 4 + r);
#pragma unroll
      for (int t2 = 0; t2 < 4; ++t2)
#pragma unroll
        for (int r = 0; r < 4; ++r) acc[t2][r] *= cfr[r];
#pragma unroll
      for (int r = 0; r < 4; ++r) accl[r] *= cfr[r];
    }
    const float mc = m_prev;
#pragma unroll
    for (int t = 0; t < 4; ++t)
#pragma unroll
      for (int r = 0; r < 4; ++r)
        s4[t][r] = __builtin_amdgcn_exp2f(s4[t][r] - mc);

    uint4 pw0, pw1;
    pw0.x = cvtpk(s4[0][0], s4[0][1]); pw0.y = cvtpk(s4[0][2], s4[0][3]);
    pw0.z = cvtpk(s4[1][0], s4[1][1]); pw0.w = cvtpk(s4[1][2], s4[1][3]);
    pw1.x = cvtpk(s4[2][0], s4[2][1]); pw1.y = cvtpk(s4[2][2], s4[2][3]);
    pw1.z = cvtpk(s4[3][0], s4[3][1]); pw1.w = cvtpk(s4[3][2], s4[3][3]);
    const bf16x8 pa0 = __builtin_bit_cast(bf16x8, pw0);
    const bf16x8 pa1 = __builtin_bit_cast(bf16x8, pw1);

    __builtin_amdgcn_s_setprio(1);
#pragma unroll
    for (int t2 = 0; t2 < 4; ++t2) {
      bf16x8 vf0 = __builtin_bit_cast(bf16x8, *(const uint4*)&Vbuf[(t2 * 16 + fr) * 64 + rc0]);
      bf16x8 vf1 = __builtin_bit_cast(bf16x8, *(const uint4*)&Vbuf[(t2 * 16 + fr) * 64 + rc1]);
      f32x4 a = acc[t2];
      a = __builtin_amdgcn_mfma_f32_16x16x32_bf16(pa0, vf0, a, 0, 0, 0);
      a = __builtin_amdgcn_mfma_f32_16x16x32_bf16(pa1, vf1, a, 0, 0, 0);
      acc[t2] = a;
    }
    {
      f32x4 a = accl;
      a = __builtin_amdgcn_mfma_f32_16x16x32_bf16(pa0, onesf, a, 0, 0, 0);
      a = __builtin_amdgcn_mfma_f32_16x16x32_bf16(pa1, onesf, a, 0, 0, 0);
      accl = a;
    }
    __builtin_amdgcn_s_setprio(0);
  };

  auto write_out = [&](int qtile) {
#pragma unroll
    for (int r = 0; r < 4; ++r) {
      float linv = 1.f / accl[r];
      size_t orow = (size_t)(b * 2048 + qtile * 64 + wq * 16 + oct * 4 + r);
#pragma unroll
      for (int t2 = 0; t2 < 4; ++t2)
        attnb[orow * 1024 + h * 64 + t2 * 16 + fr] = f2b(acc[t2][r] * linv);
    }
  };

  // ---- phase 1 staging (512 threads, 1 uint4 K + 1 uint4 V each) ----
  const int srow = tid >> 3, lc1 = tid & 7;
  const int soff = srow * 64 + (lc1 ^ (srow & 7)) * 8;  // swizzled LDS offset
  const unsigned short* kp1 = Kbase + srow * 64 + lc1 * 8;
  const unsigned short* vp1 = Vbase + srow * 64 + lc1 * 8;
  {
    uint4 kr = *(const uint4*)kp1;
    uint4 vr = *(const uint4*)vp1;
    *(uint4*)&KV[0 * 4096 + soff] = kr;
    *(uint4*)&KV[4 * 4096 + soff] = vr;
  }
  __syncthreads();

  for (int kb = 0; kb <= qt0; ++kb) {
    uint4 kr = *(const uint4*)(kp1 + (size_t)(kb + 1) * 4096);
    uint4 vr = *(const uint4*)(vp1 + (size_t)(kb + 1) * 4096);
    uint4 kr2, vr2;
    const bool extra = (kb == qt0) && (nhB > 0);
    if (extra) {  // pre-stage B's first phase-2 tile (17) into buf 2
      kr2 = *(const uint4*)(kp1 + (size_t)17 * 4096);
      vr2 = *(const uint4*)(vp1 + (size_t)17 * 4096);
    }
    tile_step(kb & 1, qa0, qa1, kb == qtP1);
    const int nb = (kb + 1) & 1;
    *(uint4*)&KV[nb * 4096 + soff] = kr;
    *(uint4*)&KV[(4 + nb) * 4096 + soff] = vr;
    if (extra) {
      *(uint4*)&KV[2 * 4096 + soff] = kr2;
      *(uint4*)&KV[6 * 4096 + soff] = vr2;
    }
    __syncthreads();
  }

  // group A: flush qt0 output, reset state for phase-2 partial
  if (grp == 0) {
    write_out(qt0);
    m_prev = -1e30f;
    f32x4 zz = {};
    accl = zz;
#pragma unroll
    for (int t2 = 0; t2 < 4; ++t2) acc[t2] = zz;
  }

  // ---- phase 2: A takes kb=qt0+1..16, B takes kb=17..qt1 ----
  const int t2id = tid & 255;
  const int sk2 = t2id >> 2, lq = t2id & 3;
  const int lcA = lq * 2, lcB = lq * 2 + 1;  // logical chunks of the 2 uint4s
  const int ofA = sk2 * 64 + (lcA ^ (sk2 & 7)) * 8;
  const int ofB = sk2 * 64 + (lcB ^ (sk2 & 7)) * 8;
  const int sc2 = lq * 16;
  const int cnt = grp ? nhB : nhA;
  for (int i = 0; i < nhA; ++i) {
    const int kbm = grp ? (17 + i) : (qt0 + 1 + i);
    const int buf = grp ? (2 + (i & 1)) : (kbm & 1);
    uint4 k0, k1, v0, v1;
    const bool pf = (i + 1 < cnt);
    if (pf) {
      const unsigned short* ks = Kbase + (size_t)((kbm + 1) * 64 + sk2) * 64 + sc2;
      const unsigned short* vs = Vbase + (size_t)((kbm + 1) * 64 + sk2) * 64 + sc2;
      k0 = *(const uint4*)ks; k1 = *(const uint4*)(ks + 8);
      v0 = *(const uint4*)vs; v1 = *(const uint4*)(vs + 8);
    }
    if (i < cnt) tile_step(buf, qb0, qb1, kbm == qt1);
    if (pf) {
      const int nb = grp ? (2 + ((i + 1) & 1)) : ((kbm + 1) & 1);
      *(uint4*)&KV[nb * 4096 + ofA] = k0;
      *(uint4*)&KV[nb * 4096 + ofB] = k1;
      *(uint4*)&KV[(4 + nb) * 4096 + ofA] = v0;
      *(uint4*)&KV[(4 + nb) * 4096 + ofB] = v1;
    }
    __syncthreads();
  }

  // ---- merge partials (B -> LDS overlay, A combines and writes qt1) ----
  float* MF = (float*)KV;  // overlays dead K/V buffers (17920 B <= 32768 B)
  if (grp == 1) {
#pragma unroll
    for (int t2 = 0; t2 < 4; ++t2)
#pragma unroll
      for (int r = 0; r < 4; ++r)
        MF[(wq * 16 + oct * 4 + r) * 68 + t2 * 16 + fr] = acc[t2][r];
    if (fr == 0) {
#pragma unroll
      for (int r = 0; r < 4; ++r) MF[4352 + wq * 16 + oct * 4 + r] = accl[r];
    }
    if (oct == 0) MF[4416 + wq * 16 + fr] = m_prev;
  }
  __syncthreads();
  if (grp == 0) {
    float mB = MF[4416 + wq * 16 + fr];
    float mS = fmaxf(m_prev, mB);
    float fA = __builtin_amdgcn_exp2f(m_prev - mS);
    float fB = __builtin_amdgcn_exp2f(mB - mS);
    float fAr[4], fBr[4];
#pragma unroll
    for (int r = 0; r < 4; ++r) {
      fAr[r] = __shfl(fA, oct * 4 + r);
      fBr[r] = __shfl(fB, oct * 4 + r);
    }
#pragma unroll
    for (int r = 0; r < 4; ++r)
      accl[r] = accl[r] * fAr[r] + MF[4352 + wq * 16 + oct * 4 + r] * fBr[r];
#pragma unroll
    for (int t2 = 0; t2 < 4; ++t2)
#pragma unroll
      for (int r = 0; r < 4; ++r)
        acc[t2][r] = acc[t2][r] * fAr[r] +
                     MF[(wq * 16 + oct * 4 + r) * 68 + t2 * 16 + fr] * fBr[r];
    write_out(qt1);
  }
}

// ---------------------------------------------------------------------------
extern "C" void kernel_launch(void* const* d_in, const int* in_sizes, int n_in,
                              void* d_out, int out_size, void* d_ws, size_t ws_size,
                              hipStream_t stream) {
  const float* x     = (const float*)d_in[0];  // [2,2048,1024]
  const float* w_qkv = (const float*)d_in[1];  // [1024,3072]
  const float* w_out = (const float*)d_in[2];  // [1024,1024]
  const float* freqs = (const float*)d_in[3];  // [2048,64]
  float* out = (float*)d_out;

  char* ws = (char*)d_ws;
  unsigned short* Qb   = (unsigned short*)(ws + 25165824);  // 8388608
  unsigned short* Kb   = (unsigned short*)(ws + 33554432);  // 8388608
  unsigned short* Vtg  = (unsigned short*)(ws + 41943040);  // 8388608
  unsigned short* attnb= (unsigned short*)(ws + 50331648);  // 8388608
  unsigned short* wqT  = (unsigned short*)(ws + 58720256);  // 6291456
  unsigned short* woT  = (unsigned short*)(ws + 65011712);  // 2097152
  unsigned short* xb   = (unsigned short*)(ws + 67108864);  // 8388608
  float* cosT          = (float*)(ws + 75497472);           // 524288
  float* sinT          = (float*)(ws + 76021760);           // 524288
  // total ws use: 76546048 bytes (~73 MiB)

  (void)hipFuncSetAttribute((const void*)gemm_fused,
                            hipFuncAttributeMaxDynamicSharedMemorySize, 49152);
  (void)hipFuncSetAttribute((const void*)gemm2_ring,
                            hipFuncAttributeMaxDynamicSharedMemorySize, 49152);
  (void)hipFuncSetAttribute((const void*)attn_mfma,
                            hipFuncAttributeMaxDynamicSharedMemorySize, 65536);

  prologue_kernel<<<8704, 256, 0, stream>>>(x, xb, freqs, cosT, sinT, w_qkv,
                                            wqT, w_out, woT);
  gemm_fused<<<dim3(24, 32), 512, 49152, stream>>>(xb, wqT, Qb, Kb, Vtg, cosT,
                                                   sinT);
  attn_mfma<<<dim3(16, 16, 2), 512, 65536, stream>>>(Qb, Kb, Vtg, attnb);
  gemm2_ring<<<dim3(16, 32), 256, 49152, stream>>>(attnb, woT, out, 4096, 1024, 1024);
}

// Round 26
// 91.576 us; speedup vs baseline: 1.0175x; 1.0175x over previous
//
#include <hip/hip_runtime.h>

// ---------------------------------------------------------------------------
// Fused attention block: qkv GEMM+RoPE+layout -> causal SDPA (MFMA) -> out GEMM
// B=2 S=2048 D=1024 H=16 DH=64. bf16 MFMA everywhere.
// MFMA fragment mapping (verified r1-r13): A/B-frag outer=lane&15, k=oct*8+e;
// C/D row=oct*4+r, col=lane&15.
// r26: gemm_fused -> gemm8: 256x256 tile, BK=64, 512 thr (2Mx4N waves,
//      per-wave 128x64, acc 8x4). 2 LDS buffers x {A,B}x{k-lo,k-hi [256][32]}
//      = 128 KB. Per K-tile 2 half-phases; counted vmcnt(4) per HP (never
//      drains; only final HP uses 0); per-HP stage of same-kh units of t+1.
//      XOR chunk swizzle chunk^((row>>1)&3) (proven ~0-conflict). Epilogue:
//      r25 RoPE math; V via two-pass 128x66 vtiles + r23-verified write.
//      attn/gemm2/prologue byte-identical to r25 (93.0-93.2us best).
// ---------------------------------------------------------------------------

typedef __bf16 bf16x8 __attribute__((ext_vector_type(8)));
typedef float f32x4 __attribute__((ext_vector_type(4)));

__device__ __forceinline__ unsigned short f2b(float f) {
  unsigned int u = __builtin_bit_cast(unsigned int, f);
  unsigned int lsb = (u >> 16) & 1u;
  u += 0x7fffu + lsb;  // round-to-nearest-even
  return (unsigned short)(u >> 16);
}
__device__ __forceinline__ float b2f(unsigned short h) {
  unsigned int u = ((unsigned int)h) << 16;
  return __builtin_bit_cast(float, u);
}
__device__ __forceinline__ unsigned int pk2(float a, float b) {
  return (unsigned int)f2b(a) | ((unsigned int)f2b(b) << 16);
}
__device__ __forceinline__ unsigned int cvtpk(float lo, float hi) {
  unsigned int r;
  asm("v_cvt_pk_bf16_f32 %0, %1, %2" : "=v"(r) : "v"(lo), "v"(hi));
  return r;
}
__device__ __forceinline__ void gload16(const void* g, void* l) {
  __builtin_amdgcn_global_load_lds(
      (const __attribute__((address_space(1))) unsigned int*)g,
      (__attribute__((address_space(3))) unsigned int*)l, 16, 0, 0);
}

// ---- fused prologue: convert | trig table | transpose wq | transpose wo ----
__global__ __launch_bounds__(256) void prologue_kernel(
    const float* __restrict__ x, unsigned short* __restrict__ xb,
    const float* __restrict__ freqs, float* __restrict__ cosT,
    float* __restrict__ sinT, const float* __restrict__ w_qkv,
    unsigned short* __restrict__ wqT, const float* __restrict__ w_out,
    unsigned short* __restrict__ woT) {
  __shared__ float tile[32][33];
  const int blk = blockIdx.x, tid = threadIdx.x;

  if (blk < 4096) {  // convert x (f32) -> xb (bf16), 4 elems/thread
    int i = (blk * 256 + tid) * 4;
    float4 v = *(const float4*)&x[i];
    ushort4 o;
    o.x = f2b(v.x); o.y = f2b(v.y); o.z = f2b(v.z); o.w = f2b(v.w);
    *(ushort4*)&xb[i] = o;
    return;
  }
  if (blk < 4608) {  // cos/sin tables (131072 elems)
    int i = (blk - 4096) * 256 + tid;
    float f = freqs[i];
    cosT[i] = cosf(f);
    sinT[i] = sinf(f);
    return;
  }
  // transpose [K][N] f32 -> [N][K] bf16
  const float* src;
  unsigned short* dst;
  int K, N, bx, by;
  if (blk < 7680) {
    src = w_qkv; dst = wqT; K = 1024; N = 3072;
    const int t = blk - 4608;
    bx = t % 96; by = t / 96;
  } else {
    src = w_out; dst = woT; K = 1024; N = 1024;
    const int t = blk - 7680;
    bx = t % 32; by = t / 32;
  }
  const int n0 = bx * 32, k0 = by * 32;
  const int c = tid & 31, r4 = tid >> 5;
#pragma unroll
  for (int p = 0; p < 4; ++p) {
    int r = r4 + p * 8;
    tile[r][c] = src[(size_t)(k0 + r) * N + n0 + c];
  }
  __syncthreads();
#pragma unroll
  for (int p = 0; p < 4; ++p) {
    int r = r4 + p * 8;
    dst[(size_t)(n0 + r) * K + k0 + c] = f2b(tile[c][r]);
  }
}

// ---- gemm8: fused qkv GEMM + RoPE + layout, 256x256 / BK=64 / 8-HP sched ---
// 512 thr = 8 waves (2M x 4N); wave (wr=w>>2, wcn=w&3) owns rows wr*128..+127,
// cols wcn*64..+63 (one head). LDS: 2 buffers x {Alo,Ahi,Blo,Bhi}[256][32]
// (each 16KB, chunk^((row>>1)&3) swizzle) = 128 KB. Per K-tile t (buf=t&1),
// 2 half-phases kh: vmcnt(4) -> barrier -> 12 ds_read -> stage 4 issues of
// tile t+1's kh-units into buf^1 -> 32 MFMA. Counted vmcnt never drains
// except the final HP. Grid (12,16)=192 blocks (1/CU), XCD-swizzled.
__global__ __launch_bounds__(512, 2) void gemm8(
    const unsigned short* __restrict__ A, const unsigned short* __restrict__ BT,
    unsigned short* __restrict__ Qb, unsigned short* __restrict__ Kbp,
    unsigned short* __restrict__ Vtg, const float* __restrict__ cosT,
    const float* __restrict__ sinT) {
  extern __shared__ unsigned short L[];  // 65536 ushorts = 128 KB
  const int K = 1024;
  const int tid = threadIdx.x, lane = tid & 63, w = tid >> 6;
  const int wr = w >> 2, wcn = w & 3;
  const int fr = lane & 15, oct = lane >> 4;

  // XCD-bijective block swizzle (192 = 8 x 24)
  const int raw = blockIdx.y * 12 + blockIdx.x;
  const int swz = (raw & 7) * 24 + (raw >> 3);
  const int m0 = (swz / 12) * 256, n0 = (swz % 12) * 256;

  // staging coordinates: thread -> row tid>>2 (0..127 within a 128-row half),
  // physical chunk tid&3, swizzled source chunk (tid&3)^((tid>>3)&3)
  const int sRow = tid >> 2;
  const int scol = ((tid & 3) ^ ((tid >> 3) & 3)) * 8;  // swizzled src col
  const int sOff = sRow * 32 + (tid & 3) * 8;           // LDS ushort offset
  const size_t aS0 = (size_t)(m0 + sRow) * K + scol;
  const size_t aS1 = (size_t)(m0 + 128 + sRow) * K + scol;
  const size_t bS0 = (size_t)(n0 + sRow) * K + scol;
  const size_t bS1 = (size_t)(n0 + 128 + sRow) * K + scol;

  // read-side swizzled chunk offsets (loop-invariant: (row>>1)&3 == (fr>>1)&3)
  const int pcx = (oct ^ ((fr >> 1) & 3)) * 8;

  f32x4 acc[8][4] = {};
  const int NT = 16;  // K / 64

  // prologue: stage tile 0 (buf 0): order Alo,Alo,Blo,Blo, Ahi,Ahi,Bhi,Bhi
#pragma unroll
  for (int kh = 0; kh < 2; ++kh) {
    const size_t gk = (size_t)kh * 32;
    gload16(&A[aS0 + gk], &L[kh * 8192 + sOff]);
    gload16(&A[aS1 + gk], &L[kh * 8192 + 4096 + sOff]);
    gload16(&BT[bS0 + gk], &L[16384 + kh * 8192 + sOff]);
    gload16(&BT[bS1 + gk], &L[16384 + kh * 8192 + 4096 + sOff]);
  }

  for (int t = 0; t < NT; ++t) {
    const int buf = t & 1, nbuf = buf ^ 1;
    const bool doStage = (t + 1 < NT);
#pragma unroll
    for (int kh = 0; kh < 2; ++kh) {
      if (t == NT - 1 && kh == 1) {
        asm volatile("s_waitcnt vmcnt(0)" ::: "memory");
      } else {
        asm volatile("s_waitcnt vmcnt(4)" ::: "memory");
      }
      __builtin_amdgcn_sched_barrier(0);
      __builtin_amdgcn_s_barrier();
      __builtin_amdgcn_sched_barrier(0);

      const unsigned short* Ab = &L[buf * 32768 + kh * 8192];
      const unsigned short* Bb = &L[buf * 32768 + 16384 + kh * 8192];

      bf16x8 af[8], bq[4];
#pragma unroll
      for (int i = 0; i < 8; ++i) {
        const int row = wr * 128 + i * 16 + fr;
        af[i] = __builtin_bit_cast(bf16x8, *(const uint4*)&Ab[row * 32 + pcx]);
      }
#pragma unroll
      for (int c = 0; c < 4; ++c) {
        const int brow = wcn * 64 + c * 16 + fr;
        bq[c] = __builtin_bit_cast(bf16x8, *(const uint4*)&Bb[brow * 32 + pcx]);
      }
      if (doStage) {  // stage tile t+1's kh-units into nbuf (A,A,B,B order)
        const size_t gk = (size_t)(t + 1) * 64 + kh * 32;
        unsigned short* D = &L[nbuf * 32768 + kh * 8192];
        gload16(&A[aS0 + gk], &D[sOff]);
        gload16(&A[aS1 + gk], &D[4096 + sOff]);
        gload16(&BT[bS0 + gk], &D[16384 + sOff]);
        gload16(&BT[bS1 + gk], &D[16384 + 4096 + sOff]);
      }
      __builtin_amdgcn_s_setprio(1);
#pragma unroll
      for (int i = 0; i < 8; ++i)
#pragma unroll
        for (int c = 0; c < 4; ++c)
          acc[i][c] = __builtin_amdgcn_mfma_f32_16x16x32_bf16(af[i], bq[c], acc[i][c], 0, 0, 0);
      __builtin_amdgcn_s_setprio(0);
    }
  }

  // ---- fused epilogue ----
  const float QSCALE = 0.125f * 1.44269504f;
  const int part = n0 >> 10;               // block-uniform (256 | 1024)
  const int hbase = (n0 & 1023) >> 6;
  if (part < 2) {
    unsigned short* dst = (part == 0) ? Qb : Kbp;
    const float scale = (part == 0) ? QSCALE : 1.0f;
    const int hh = hbase + wcn;
#pragma unroll
    for (int i = 0; i < 8; ++i)
#pragma unroll
      for (int r = 0; r < 4; ++r) {
        const int m = m0 + wr * 128 + i * 16 + oct * 4 + r;
        const int bb = m >> 11, s = m & 2047;
        const size_t ob = ((size_t)(bb * 16 + hh) * 2048 + s) * 64;
#pragma unroll
        for (int j = 0; j < 2; ++j) {
          const int d = j * 16 + fr;
          const float lo = acc[i][j][r], hi = acc[i][j + 2][r];
          const float cl = cosT[s * 64 + d], sl = sinT[s * 64 + d];
          const float ch = cosT[s * 64 + 32 + d], sh = sinT[s * 64 + 32 + d];
          dst[ob + d] = f2b((lo * cl - hi * sl) * scale);
          dst[ob + 32 + d] = f2b((hi * ch + lo * sh) * scale);
        }
      }
  } else {
    // V: two passes; pass p: waves wr==p stage 4 vtiles [128][66], then all
    // 512 threads do the transposed + k-permuted write (r23-verified map).
#pragma unroll
    for (int p = 0; p < 2; ++p) {
      __syncthreads();
      if (wr == p) {
        unsigned short* vt = L + wcn * 8448;  // 128*66
#pragma unroll
        for (int i = 0; i < 8; ++i)
#pragma unroll
          for (int r = 0; r < 4; ++r) {
            const int row = i * 16 + oct * 4 + r;
#pragma unroll
            for (int j = 0; j < 4; ++j)
              vt[row * 66 + j * 16 + fr] = f2b(acc[i][j][r]);
          }
      }
      __syncthreads();
      const int sidx = tid >> 6, d = tid & 63;
      const int hd = sidx & 3, mgl = sidx >> 2;  // head, 64-row group in pass
      const unsigned short* tt = L + hd * 8448 + mgl * 64 * 66;
      const int mtile = m0 + (p * 2 + mgl) * 64;
      const int bb = mtile >> 11, sb = (mtile & 2047) >> 6;
      const int hv = hbase + hd;
      const size_t vb = (((size_t)(bb * 16 + hv) * 32 + sb) * 64 + d) * 64;
#pragma unroll
      for (int qq = 0; qq < 4; ++qq)
#pragma unroll
        for (int g = 0; g < 4; ++g) {
          ushort4 u;
          u.x = tt[(qq * 16 + g * 4 + 0) * 66 + d];
          u.y = tt[(qq * 16 + g * 4 + 1) * 66 + d];
          u.z = tt[(qq * 16 + g * 4 + 2) * 66 + d];
          u.w = tt[(qq * 16 + g * 4 + 3) * 66 + d];
          *(ushort4*)&Vtg[vb + (qq >> 1) * 32 + g * 8 + (qq & 1) * 4] = u;
        }
    }
  }
}

// ---------------- ring-buffered bf16 GEMM for out GEMM (f32 C) -------------
__global__ __launch_bounds__(256, 2) void gemm2_ring(const unsigned short* __restrict__ A,
                                                     const unsigned short* __restrict__ BT,
                                                     float* __restrict__ C,
                                                     int M, int N, int K) {
  extern __shared__ unsigned short L[];  // 4 slots x 6144 ushort = 48 KB
  const int tid = threadIdx.x, lane = tid & 63, w = tid >> 6;
  const int wr = w >> 1, wc = w & 1;
  const int fr = lane & 15, oct = lane >> 4;
  const int m0 = blockIdx.y * 128, n0 = blockIdx.x * 64;

  const int sr = tid >> 2;
  const int scol = ((tid & 3) ^ ((tid >> 3) & 3)) * 8;  // swizzled src col
  const size_t aR0 = (size_t)(m0 + sr) * K + scol;
  const size_t aR1 = (size_t)(m0 + 64 + sr) * K + scol;
  const size_t bR0 = (size_t)(n0 + sr) * K + scol;

  f32x4 acc[4][2] = {};
  const int T = K >> 5;

  for (int pt = 0; pt < 3; ++pt) {  // prologue: stage tiles 0,1,2
    unsigned short* Ln = &L[pt * 6144];
    const size_t gk = (size_t)pt * 32;
    gload16(&A[aR0 + gk], &Ln[tid * 8]);
    gload16(&A[aR1 + gk], &Ln[2048 + tid * 8]);
    gload16(&BT[bR0 + gk], &Ln[4096 + tid * 8]);
  }

  for (int t = 0; t < T; ++t) {
    if (t + 3 <= T) {
      asm volatile("s_waitcnt vmcnt(6)" ::: "memory");
    } else if (t + 2 == T) {
      asm volatile("s_waitcnt vmcnt(3)" ::: "memory");
    } else {
      asm volatile("s_waitcnt vmcnt(0)" ::: "memory");
    }
    __builtin_amdgcn_sched_barrier(0);
    __builtin_amdgcn_s_barrier();
    __builtin_amdgcn_sched_barrier(0);

    const unsigned short* Lb = &L[(t & 3) * 6144];
    unsigned short* Ln = &L[((t + 3) & 3) * 6144];
    const size_t gk = (size_t)(t + 3) * 32;
    const bool doStage = (t + 3 < T);

    bf16x8 af[4], bq[2];
#pragma unroll
    for (int i = 0; i < 4; ++i) {
      const int ra = wr * 64 + i * 16 + fr;
      af[i] = __builtin_bit_cast(
          bf16x8, *(const uint4*)&Lb[ra * 32 + ((oct ^ ((ra >> 1) & 3)) * 8)]);
    }
#pragma unroll
    for (int j = 0; j < 2; ++j) {
      const int rb = wc * 32 + j * 16 + fr;
      bq[j] = __builtin_bit_cast(
          bf16x8,
          *(const uint4*)&Lb[4096 + rb * 32 + ((oct ^ ((rb >> 1) & 3)) * 8)]);
    }
    if (doStage) {
      gload16(&A[aR0 + gk], &Ln[tid * 8]);
      gload16(&A[aR1 + gk], &Ln[2048 + tid * 8]);
      gload16(&BT[bR0 + gk], &Ln[4096 + tid * 8]);
    }
    __builtin_amdgcn_s_setprio(1);
#pragma unroll
    for (int i = 0; i < 4; ++i)
#pragma unroll
      for (int j = 0; j < 2; ++j)
        acc[i][j] = __builtin_amdgcn_mfma_f32_16x16x32_bf16(af[i], bq[j], acc[i][j], 0, 0, 0);
    __builtin_amdgcn_s_setprio(0);
  }

#pragma unroll
  for (int i = 0; i < 4; ++i)
#pragma unroll
    for (int j = 0; j < 2; ++j)
#pragma unroll
      for (int r = 0; r < 4; ++r)
        C[(size_t)(m0 + wr * 64 + i * 16 + oct * 4 + r) * N + n0 + wc * 32 +
          j * 16 + fr] = acc[i][j][r];
}

// --------------------------- MFMA flash attention ---------------------------
// (r13 algorithm + XCD swizzle + XOR-swizzled stride-64 K/V LDS tiles)
__global__ __launch_bounds__(512, 4) void attn_mfma(const unsigned short* __restrict__ Qb,
                                                    const unsigned short* __restrict__ Kb,
                                                    const unsigned short* __restrict__ Vtg,
                                                    unsigned short* __restrict__ attnb) {
  extern __shared__ unsigned short KV[];  // [8][64][64], XOR-chunk-swizzled
  // XCD-bijective swizzle: all 16 qt0-blocks of one (h,b) K/V group -> 1 XCD
  const int bid = blockIdx.x + 16 * (blockIdx.y + 16 * blockIdx.z);
  const int xcd = bid & 7, slot = bid >> 3;
  const int qt0 = slot & 15;           // 0..15
  const int gq = xcd + 8 * (slot >> 4);  // 0..31 (h,b group)
  const int h = gq & 15, b = gq >> 4;
  const int qt1 = 31 - qt0;            // 16..31
  const int tid = threadIdx.x, lane = tid & 63, w = tid >> 6;
  const int fr = lane & 15, oct = lane >> 4;
  const int grp = w >> 2, wq = w & 3;
  const int nhA = 16 - qt0, nhB = 15 - qt0;

  const size_t bh = (size_t)(b * 16 + h);
  const unsigned short* Kbase = Kb + bh * 131072;
  const unsigned short* Vbase = Vtg + bh * 131072;

  const int qtP1 = grp ? qt1 : qt0;
  const unsigned short* Qp1 = Qb + (bh * 2048 + qtP1 * 64 + wq * 16 + fr) * 64;
  const bf16x8 qa0 = __builtin_bit_cast(bf16x8, *(const uint4*)(Qp1 + oct * 8));
  const bf16x8 qa1 = __builtin_bit_cast(bf16x8, *(const uint4*)(Qp1 + 32 + oct * 8));
  const unsigned short* Qp2 = Qb + (bh * 2048 + qt1 * 64 + wq * 16 + fr) * 64;
  const bf16x8 qb0 = __builtin_bit_cast(bf16x8, *(const uint4*)(Qp2 + oct * 8));
  const bf16x8 qb1 = __builtin_bit_cast(bf16x8, *(const uint4*)(Qp2 + 32 + oct * 8));

  // loop-invariant swizzled read-chunk offsets: row&7 == fr&7
  const int frx = fr & 7;
  const int rc0 = (oct ^ frx) * 8;        // logical chunk oct   (d 0..31)
  const int rc1 = ((4 + oct) ^ frx) * 8;  // logical chunk 4+oct (d 32..63)

  float m_prev = -1e30f;
  f32x4 acc[4] = {};
  f32x4 accl = {};

  uint4 onesu;
  onesu.x = 0x3F803F80u; onesu.y = 0x3F803F80u;
  onesu.z = 0x3F803F80u; onesu.w = 0x3F803F80u;
  const bf16x8 onesf = __builtin_bit_cast(bf16x8, onesu);

  auto tile_step = [&](int buf, bf16x8 q0, bf16x8 q1, bool domask) {
    const unsigned short* Kbuf = &KV[buf * 4096];
    const unsigned short* Vbuf = &KV[(4 + buf) * 4096];
    f32x4 s4[4];
    __builtin_amdgcn_s_setprio(1);
#pragma unroll
    for (int t = 0; t < 4; ++t) {
      bf16x8 kf0 = __builtin_bit_cast(bf16x8, *(const uint4*)&Kbuf[(t * 16 + fr) * 64 + rc0]);
      bf16x8 kf1 = __builtin_bit_cast(bf16x8, *(const uint4*)&Kbuf[(t * 16 + fr) * 64 + rc1]);
      f32x4 s = {};
      s = __builtin_amdgcn_mfma_f32_16x16x32_bf16(kf0, q0, s, 0, 0, 0);
      s = __builtin_amdgcn_mfma_f32_16x16x32_bf16(kf1, q1, s, 0, 0, 0);
      s4[t] = s;
    }
    __builtin_amdgcn_s_setprio(0);
    if (domask) {
#pragma unroll
      for (int t = 0; t < 4; ++t)
#pragma unroll
        for (int r = 0; r < 4; ++r)
          if (t * 16 + oct * 4 + r > wq * 16 + fr) s4[t][r] = -1e30f;
    }

    float pm = -1e30f;
#pragma unroll
    for (int t = 0; t < 4; ++t)
#pragma unroll
      for (int r = 0; r < 4; ++r) pm = fmaxf(pm, s4[t][r]);
    const bool need = __any(pm - m_prev > 11.0f);
    if (need) {
      float pmf = fmaxf(pm, __shfl_xor(pm, 16));
      pmf = fmaxf(pmf, __shfl_xor(pmf, 32));
      float mnew = fmaxf(m_prev, pmf);
      float cf = __builtin_amdgcn_exp2f(m_prev - mnew);
      m_prev = mnew;
      float cfr[4];
#pragma unroll
      for (int r = 0; r < 4; ++r) cfr[r] = __shfl(cf, oct * 4 + r);
#pragma unroll
      for (int t2 = 0; t2 < 4; ++t2)
#pragma unroll
        for (int r = 0; r < 4; ++r) acc[t2][r] *= cfr[r];
#pragma unroll
      for (int r = 0; r < 4; ++r) accl[r] *= cfr[r];
    }
    const float mc = m_prev;
#pragma unroll
    for (int t = 0; t < 4; ++t)
#pragma unroll
      for (int r = 0; r < 4; ++r)
        s4[t][r] = __builtin_amdgcn_exp2f(s4[t][r] - mc);

    uint4 pw0, pw1;
    pw0.x = cvtpk(s4[0][0], s4[0][1]); pw0.y = cvtpk(s4[0][2], s4[0][3]);
    pw0.z = cvtpk(s4[1][0], s4[1][1]); pw0.w = cvtpk(s4[1][2], s4[1][3]);
    pw1.x = cvtpk(s4[2][0], s4[2][1]); pw1.y = cvtpk(s4[2][2], s4[2][3]);
    pw1.z = cvtpk(s4[3][0], s4[3][1]); pw1.w = cvtpk(s4[3][2], s4[3][3]);
    const bf16x8 pa0 = __builtin_bit_cast(bf16x8, pw0);
    const bf16x8 pa1 = __builtin_bit_cast(bf16x8, pw1);

    __builtin_amdgcn_s_setprio(1);
#pragma unroll
    for (int t2 = 0; t2 < 4; ++t2) {
      bf16x8 vf0 = __builtin_bit_cast(bf16x8, *(const uint4*)&Vbuf[(t2 * 16 + fr) * 64 + rc0]);
      bf16x8 vf1 = __builtin_bit_cast(bf16x8, *(const uint4*)&Vbuf[(t2 * 16 + fr) * 64 + rc1]);
      f32x4 a = acc[t2];
      a = __builtin_amdgcn_mfma_f32_16x16x32_bf16(pa0, vf0, a, 0, 0, 0);
      a = __builtin_amdgcn_mfma_f32_16x16x32_bf16(pa1, vf1, a, 0, 0, 0);
      acc[t2] = a;
    }
    {
      f32x4 a = accl;
      a = __builtin_amdgcn_mfma_f32_16x16x32_bf16(pa0, onesf, a, 0, 0, 0);
      a = __builtin_amdgcn_mfma_f32_16x16x32_bf16(pa1, onesf, a, 0, 0, 0);
      accl = a;
    }
    __builtin_amdgcn_s_setprio(0);
  };

  auto write_out = [&](int qtile) {
#pragma unroll
    for (int r = 0; r < 4; ++r) {
      float linv = 1.f / accl[r];
      size_t orow = (size_t)(b * 2048 + qtile * 64 + wq * 16 + oct * 4 + r);
#pragma unroll
      for (int t2 = 0; t2 < 4; ++t2)
        attnb[orow * 1024 + h * 64 + t2 * 16 + fr] = f2b(acc[t2][r] * linv);
    }
  };

  // ---- phase 1 staging (512 threads, 1 uint4 K + 1 uint4 V each) ----
  const int srow = tid >> 3, lc1 = tid & 7;
  const int soff = srow * 64 + (lc1 ^ (srow & 7)) * 8;  // swizzled LDS offset
  const unsigned short* kp1 = Kbase + srow * 64 + lc1 * 8;
  const unsigned short* vp1 = Vbase + srow * 64 + lc1 * 8;
  {
    uint4 kr = *(const uint4*)kp1;
    uint4 vr = *(const uint4*)vp1;
    *(uint4*)&KV[0 * 4096 + soff] = kr;
    *(uint4*)&KV[4 * 4096 + soff] = vr;
  }
  __syncthreads();

  for (int kb = 0; kb <= qt0; ++kb) {
    uint4 kr = *(const uint4*)(kp1 + (size_t)(kb + 1) * 4096);
    uint4 vr = *(const uint4*)(vp1 + (size_t)(kb + 1) * 4096);
    uint4 kr2, vr2;
    const bool extra = (kb == qt0) && (nhB > 0);
    if (extra) {  // pre-stage B's first phase-2 tile (17) into buf 2
      kr2 = *(const uint4*)(kp1 + (size_t)17 * 4096);
      vr2 = *(const uint4*)(vp1 + (size_t)17 * 4096);
    }
    tile_step(kb & 1, qa0, qa1, kb == qtP1);
    const int nb = (kb + 1) & 1;
    *(uint4*)&KV[nb * 4096 + soff] = kr;
    *(uint4*)&KV[(4 + nb) * 4096 + soff] = vr;
    if (extra) {
      *(uint4*)&KV[2 * 4096 + soff] = kr2;
      *(uint4*)&KV[6 * 4096 + soff] = vr2;
    }
    __syncthreads();
  }

  // group A: flush qt0 output, reset state for phase-2 partial
  if (grp == 0) {
    write_out(qt0);
    m_prev = -1e30f;
    f32x4 zz = {};
    accl = zz;
#pragma unroll
    for (int t2 = 0; t2 < 4; ++t2) acc[t2] = zz;
  }

  // ---- phase 2: A takes kb=qt0+1..16, B takes kb=17..qt1 ----
  const int t2id = tid & 255;
  const int sk2 = t2id >> 2, lq = t2id & 3;
  const int lcA = lq * 2, lcB = lq * 2 + 1;  // logical chunks of the 2 uint4s
  const int ofA = sk2 * 64 + (lcA ^ (sk2 & 7)) * 8;
  const int ofB = sk2 * 64 + (lcB ^ (sk2 & 7)) * 8;
  const int sc2 = lq * 16;
  const int cnt = grp ? nhB : nhA;
  for (int i = 0; i < nhA; ++i) {
    const int kbm = grp ? (17 + i) : (qt0 + 1 + i);
    const int buf = grp ? (2 + (i & 1)) : (kbm & 1);
    uint4 k0, k1, v0, v1;
    const bool pf = (i + 1 < cnt);
    if (pf) {
      const unsigned short* ks = Kbase + (size_t)((kbm + 1) * 64 + sk2) * 64 + sc2;
      const unsigned short* vs = Vbase + (size_t)((kbm + 1) * 64 + sk2) * 64 + sc2;
      k0 = *(const uint4*)ks; k1 = *(const uint4*)(ks + 8);
      v0 = *(const uint4*)vs; v1 = *(const uint4*)(vs + 8);
    }
    if (i < cnt) tile_step(buf, qb0, qb1, kbm == qt1);
    if (pf) {
      const int nb = grp ? (2 + ((i + 1) & 1)) : ((kbm + 1) & 1);
      *(uint4*)&KV[nb * 4096 + ofA] = k0;
      *(uint4*)&KV[nb * 4096 + ofB] = k1;
      *(uint4*)&KV[(4 + nb) * 4096 + ofA] = v0;
      *(uint4*)&KV[(4 + nb) * 4096 + ofB] = v1;
    }
    __syncthreads();
  }

  // ---- merge partials (B -> LDS overlay, A combines and writes qt1) ----
  float* MF = (float*)KV;  // overlays dead K/V buffers (17920 B <= 32768 B)
  if (grp == 1) {
#pragma unroll
    for (int t2 = 0; t2 < 4; ++t2)
#pragma unroll
      for (int r = 0; r < 4; ++r)
        MF[(wq * 16 + oct * 4 + r) * 68 + t2 * 16 + fr] = acc[t2][r];
    if (fr == 0) {
#pragma unroll
      for (int r = 0; r < 4; ++r) MF[4352 + wq * 16 + oct * 4 + r] = accl[r];
    }
    if (oct == 0) MF[4416 + wq * 16 + fr] = m_prev;
  }
  __syncthreads();
  if (grp == 0) {
    float mB = MF[4416 + wq * 16 + fr];
    float mS = fmaxf(m_prev, mB);
    float fA = __builtin_amdgcn_exp2f(m_prev - mS);
    float fB = __builtin_amdgcn_exp2f(mB - mS);
    float fAr[4], fBr[4];
#pragma unroll
    for (int r = 0; r < 4; ++r) {
      fAr[r] = __shfl(fA, oct * 4 + r);
      fBr[r] = __shfl(fB, oct * 4 + r);
    }
#pragma unroll
    for (int r = 0; r < 4; ++r)
      accl[r] = accl[r] * fAr[r] + MF[4352 + wq * 16 + oct * 4 + r] * fBr[r];
#pragma unroll
    for (int t2 = 0; t2 < 4; ++t2)
#pragma unroll
      for (int r = 0; r < 4; ++r)
        acc[t2][r] = acc[t2][r] * fAr[r] +
                     MF[(wq * 16 + oct * 4 + r) * 68 + t2 * 16 + fr] * fBr[r];
    write_out(qt1);
  }
}

// ---------------------------------------------------------------------------
extern "C" void kernel_launch(void* const* d_in, const int* in_sizes, int n_in,
                              void* d_out, int out_size, void* d_ws, size_t ws_size,
                              hipStream_t stream) {
  const float* x     = (const float*)d_in[0];  // [2,2048,1024]
  const float* w_qkv = (const float*)d_in[1];  // [1024,3072]
  const float* w_out = (const float*)d_in[2];  // [1024,1024]
  const float* freqs = (const float*)d_in[3];  // [2048,64]
  float* out = (float*)d_out;

  char* ws = (char*)d_ws;
  unsigned short* Qb   = (unsigned short*)(ws + 25165824);  // 8388608
  unsigned short* Kb   = (unsigned short*)(ws + 33554432);  // 8388608
  unsigned short* Vtg  = (unsigned short*)(ws + 41943040);  // 8388608
  unsigned short* attnb= (unsigned short*)(ws + 50331648);  // 8388608
  unsigned short* wqT  = (unsigned short*)(ws + 58720256);  // 6291456
  unsigned short* woT  = (unsigned short*)(ws + 65011712);  // 2097152
  unsigned short* xb   = (unsigned short*)(ws + 67108864);  // 8388608
  float* cosT          = (float*)(ws + 75497472);           // 524288
  float* sinT          = (float*)(ws + 76021760);           // 524288
  // total ws use: 76546048 bytes (~73 MiB)

  (void)hipFuncSetAttribute((const void*)gemm8,
                            hipFuncAttributeMaxDynamicSharedMemorySize, 131072);
  (void)hipFuncSetAttribute((const void*)gemm2_ring,
                            hipFuncAttributeMaxDynamicSharedMemorySize, 49152);
  (void)hipFuncSetAttribute((const void*)attn_mfma,
                            hipFuncAttributeMaxDynamicSharedMemorySize, 65536);

  prologue_kernel<<<8704, 256, 0, stream>>>(x, xb, freqs, cosT, sinT, w_qkv,
                                            wqT, w_out, woT);
  gemm8<<<dim3(12, 16), 512, 131072, stream>>>(xb, wqT, Qb, Kb, Vtg, cosT,
                                               sinT);
  attn_mfma<<<dim3(16, 16, 2), 512, 65536, stream>>>(Qb, Kb, Vtg, attnb);
  gemm2_ring<<<dim3(16, 32), 256, 49152, stream>>>(attnb, woT, out, 4096, 1024, 1024);
}